// Round 5
// baseline (3222.256 us; speedup 1.0000x reference)
//
#include <hip/hip_runtime.h>
#include <hip/hip_bf16.h>

// ---------------------------------------------------------------------------
// RNN: h_{t+1} = tanh(Wx[t] + h_t @ W_h + b_h),  Wx = X @ W_enc + b_enc
// T=512 B=128 D_IN=512 D_H=1024. fp16 MFMA (16x16x32), fp32 accumulate.
//
// R5 = R4 (flagless tagged-data scan) + SELECTIVE RETRY in the spin loop:
//   each thread keeps a 32-bit stale mask and re-issues uncached loads ONLY
//   for granules whose tag failed. R4 re-read the whole 64 KB slab per round
//   (~25-30 MB/step through the coherent point = self-inflicted queueing).
//   Topology: 128 WGs = 4 groups x 32; group g owns batches [32g,32g+32);
//   WG (g,w) owns h-cols [32w,32w+32), W_h slice pinned in LDS. 8B granules
//   carry step-tag (mod 4) in fp16 LSBs, replicated per dword.
// ---------------------------------------------------------------------------

typedef _Float16 f16;
typedef f16 f16x8 __attribute__((ext_vector_type(8)));
typedef f16 f16x4 __attribute__((ext_vector_type(4)));
typedef float f32x4 __attribute__((ext_vector_type(4)));
typedef unsigned long long u64;

#define T_STEPS 512
#define BATCH   128
#define D_IN    512
#define D_H     1024
#define BH      (BATCH * D_H)

// ---- workspace layout (bytes) ----
#define WX_OFF    0                         // fp16 Wx [512][128][1024] = 134217728
#define WENC_OFF  (134217728)               // fp16 W_encT [1024][512]  = 1048576
#define WH_OFF    (WENC_OFF + 1048576)      // fp16 W_hT   [1024][1024] = 2097152
#define HBUF_OFF  (WH_OFF + 2097152)        // fp16 hbuf [2][128][1024] = 524288

#define LDSTR   1032    // fp16 row stride (pad +8: 16B-aligned rows, 2-way banks)

// tag bits: LSB of each fp16 lane of the 8B granule
#define TAGM 0x0001000100010001ULL
__device__ __forceinline__ u64 tag_pat(int s) {
    return ((u64)(s & 1)        * 0x0000000100000001ULL)
         | ((u64)((s >> 1) & 1) * 0x0001000000010000ULL);
}

// ---- relaxed agent-scope atomics: sc0/sc1 cache-bypassing, no fences ----
__device__ __forceinline__ u64 atom_ld8(const void* p) {
    return __hip_atomic_load((const u64*)p, __ATOMIC_RELAXED, __HIP_MEMORY_SCOPE_AGENT);
}
__device__ __forceinline__ void atom_st8(void* p, u64 v) {
    __hip_atomic_store((u64*)p, v, __ATOMIC_RELAXED, __HIP_MEMORY_SCOPE_AGENT);
}

#define BARRIER_LGKM() asm volatile("s_waitcnt lgkmcnt(0)\n\ts_barrier" ::: "memory")

__device__ __forceinline__ float fast_tanh(float v) {
    float ax = __builtin_fabsf(v);
    float tq = __builtin_amdgcn_exp2f(-2.8853900817779268f * ax);   // e^(-2|x|)
    float th = (1.0f - tq) * __builtin_amdgcn_rcpf(1.0f + tq);
    return __builtin_copysignf(th, v);
}

// ===========================================================================
// Phase 0: convert W_enc -> W_encT fp16, W_h -> W_hT fp16, h0 -> hbuf[0] fp16
// ===========================================================================
__global__ void convert_kernel(const float* __restrict__ Wenc,
                               const float* __restrict__ Wh,
                               const float* __restrict__ h0,
                               f16* __restrict__ WencT,
                               f16* __restrict__ WhT,
                               f16* __restrict__ hbuf0) {
    int idx = blockIdx.x * 256 + threadIdx.x;
    if (idx < D_IN * D_H) {                       // W_enc [512][1024]
        int k = idx >> 10, n = idx & 1023;
        WencT[n * D_IN + k] = (f16)Wenc[idx];
    } else if (idx < D_IN * D_H + D_H * D_H) {    // W_h [1024][1024]
        int j = idx - D_IN * D_H;
        int k = j >> 10, n = j & 1023;
        WhT[n * D_H + k] = (f16)Wh[j];
    } else if (idx < D_IN * D_H + D_H * D_H + BATCH * D_H) {
        int j = idx - (D_IN * D_H + D_H * D_H);
        f16 v = (f16)h0[j];
        unsigned short u = __builtin_bit_cast(unsigned short, v) & 0xFFFEu; // tag 0
        hbuf0[j] = __builtin_bit_cast(f16, u);
    }
}

// ===========================================================================
// Phase 1: Wx = X @ W_enc + b_enc   (M=65536, K=512, N=1024), out fp16
// ===========================================================================
__global__ __launch_bounds__(256, 2) void wx_gemm(
        const float* __restrict__ X,
        const f16*   __restrict__ WencT,
        const float* __restrict__ b_enc,
        f16*         __restrict__ Wx) {
    __shared__ f16 A_lds[128 * 72];
    __shared__ f16 B_lds[128 * 72];

    const int m0 = blockIdx.x * 128;
    const int n0 = blockIdx.y * 128;
    const int tid = threadIdx.x;
    const int wave = tid >> 6, lane = tid & 63;
    const int q = lane >> 4, r = lane & 15;
    const int wm = wave >> 1, wn = wave & 1;

    f32x4 acc[4][4] = {};

    for (int kb = 0; kb < D_IN; kb += 64) {
        #pragma unroll
        for (int i = 0; i < 8; ++i) {
            int vec = tid + i * 256;
            int m = vec >> 4, k4 = vec & 15;
            float4 f = *(const float4*)(X + (size_t)(m0 + m) * D_IN + kb + k4 * 4);
            f16x4 h4;
            h4[0] = (f16)f.x; h4[1] = (f16)f.y; h4[2] = (f16)f.z; h4[3] = (f16)f.w;
            *(f16x4*)(A_lds + m * 72 + k4 * 4) = h4;
        }
        #pragma unroll
        for (int i = 0; i < 4; ++i) {
            int vec = tid + i * 256;
            int n = vec >> 3, k8 = vec & 7;
            f16x8 v = *(const f16x8*)(WencT + (size_t)(n0 + n) * D_IN + kb + k8 * 8);
            *(f16x8*)(B_lds + n * 72 + k8 * 8) = v;
        }
        __syncthreads();
        #pragma unroll
        for (int ks = 0; ks < 2; ++ks) {
            f16x8 a[4], b[4];
            #pragma unroll
            for (int i = 0; i < 4; ++i)
                a[i] = *(const f16x8*)(A_lds + (wm * 64 + i * 16 + r) * 72 + ks * 32 + q * 8);
            #pragma unroll
            for (int j = 0; j < 4; ++j)
                b[j] = *(const f16x8*)(B_lds + (wn * 64 + j * 16 + r) * 72 + ks * 32 + q * 8);
            #pragma unroll
            for (int i = 0; i < 4; ++i)
                #pragma unroll
                for (int j = 0; j < 4; ++j)
                    acc[i][j] = __builtin_amdgcn_mfma_f32_16x16x32_f16(a[i], b[j], acc[i][j], 0, 0, 0);
        }
        __syncthreads();
    }
    #pragma unroll
    for (int j = 0; j < 4; ++j) {
        int col = n0 + wn * 64 + j * 16 + r;
        float be = b_enc[col];
        #pragma unroll
        for (int i = 0; i < 4; ++i) {
            int row = m0 + wm * 64 + i * 16 + q * 4;
            #pragma unroll
            for (int ii = 0; ii < 4; ++ii)
                Wx[(size_t)(row + ii) * D_H + col] = (f16)(acc[i][j][ii] + be);
        }
    }
}

// ===========================================================================
// Phase 2: tagged-data scan w/ selective retry. 128 WGs x 256 threads.
// ===========================================================================
extern __shared__ char smem_raw[];

__global__ __launch_bounds__(256) void rnn_steps(
        const f16*  __restrict__ WhT,    // [1024][1024] fp16 n-major
        const f16*  __restrict__ Wx,     // [512][128][1024] fp16
        const float* __restrict__ b_h,   // [1024]
        f16*        __restrict__ hbuf,   // [2][128][1024] fp16 (tagged)
        float*      __restrict__ out) {  // [128][1024] fp32
    f16* w_lds = (f16*)smem_raw;                  // [32][LDSTR]
    f16* h_lds = (f16*)smem_raw + 32 * LDSTR;     // [32][LDSTR]

    const int wg  = blockIdx.x;
    const int b0  = (wg >> 5) * 32;               // group's batch base
    const int c0  = (wg & 31) * 32;               // WG's column slice
    const int tid = threadIdx.x;
    const int wave = tid >> 6, lane = tid & 63;
    const int q = lane >> 4, r = lane & 15;
    const int ct = wave >> 1, bt = wave & 1;      // col-tile / batch-tile

    // pin W_h slice: 32 col-rows x 1024 k
    #pragma unroll
    for (int i = 0; i < 16; ++i) {
        int vec = tid + i * 256;
        int n = vec >> 7, k8 = vec & 127;
        f16x8 v = *(const f16x8*)(WhT + (size_t)(c0 + n) * D_H + k8 * 8);
        *(f16x8*)(w_lds + n * LDSTR + k8 * 8) = v;
    }
    const int colo = c0 + ct * 16 + q * 4;        // lane's 4 consecutive cols
    const float4 bhv = *(const float4*)(b_h + colo);
    const int batch = b0 + bt * 16 + r;           // lane's batch

    // prologue: speculative loads of h_0 (slot 0, tag 0 — written by convert)
    u64 buf[32];
    {
        const f16* hs = hbuf + (size_t)b0 * D_H;
        #pragma unroll
        for (int i = 0; i < 32; ++i)
            buf[i] = atom_ld8(hs + (size_t)i * D_H + tid * 4);
    }

    for (int t = 0; t < T_STEPS; ++t) {
        const u64 pat = tag_pat(t);
        const f16* hs = hbuf + (size_t)(t & 1) * BH + (size_t)b0 * D_H;

        // prefetch Wx[t] for the epilogue (cached path, overlaps the spin)
        f16x4 wxv = *(const f16x4*)(Wx + (size_t)t * BH + (size_t)batch * D_H + colo);

        // ---- validate tags; SELECTIVE retry: reload only stale granules ----
        for (;;) {
            unsigned stale = 0;
            #pragma unroll
            for (int i = 0; i < 32; ++i)
                stale |= (((buf[i] ^ pat) & TAGM) != 0 ? 1u : 0u) << i;
            if (!__any(stale != 0)) break;
            #pragma unroll
            for (int i = 0; i < 32; ++i)
                if (stale & (1u << i))
                    buf[i] = atom_ld8(hs + (size_t)i * D_H + tid * 4);
        }

        // ---- h_t -> LDS ----
        #pragma unroll
        for (int i = 0; i < 32; ++i)
            *(u64*)(h_lds + i * LDSTR + tid * 4) = buf[i];
        BARRIER_LGKM();

        // ---- MFMA: D[col][batch] = Wslice(32x1024) * h^T ----
        f32x4 acc0 = {0.f, 0.f, 0.f, 0.f}, acc1 = {0.f, 0.f, 0.f, 0.f};
        #pragma unroll
        for (int kk = 0; kk < 32; kk += 2) {
            f16x8 aw0 = *(const f16x8*)(w_lds + (ct * 16 + r) * LDSTR + kk * 32 + q * 8);
            f16x8 ah0 = *(const f16x8*)(h_lds + (bt * 16 + r) * LDSTR + kk * 32 + q * 8);
            acc0 = __builtin_amdgcn_mfma_f32_16x16x32_f16(aw0, ah0, acc0, 0, 0, 0);
            f16x8 aw1 = *(const f16x8*)(w_lds + (ct * 16 + r) * LDSTR + (kk + 1) * 32 + q * 8);
            f16x8 ah1 = *(const f16x8*)(h_lds + (bt * 16 + r) * LDSTR + (kk + 1) * 32 + q * 8);
            acc1 = __builtin_amdgcn_mfma_f32_16x16x32_f16(aw1, ah1, acc1, 0, 0, 0);
        }

        // ---- epilogue: tanh -> tagged 8B store of h_{t+1} ----
        float th0 = fast_tanh(acc0[0] + acc1[0] + (float)wxv[0] + bhv.x);
        float th1 = fast_tanh(acc0[1] + acc1[1] + (float)wxv[1] + bhv.y);
        float th2 = fast_tanh(acc0[2] + acc1[2] + (float)wxv[2] + bhv.z);
        float th3 = fast_tanh(acc0[3] + acc1[3] + (float)wxv[3] + bhv.w);

        if (t < T_STEPS - 1) {
            f16x4 hv;
            hv[0] = (f16)th0; hv[1] = (f16)th1; hv[2] = (f16)th2; hv[3] = (f16)th3;
            u64 u = (__builtin_bit_cast(u64, hv) & ~TAGM) | tag_pat(t + 1);
            f16* hn = hbuf + (size_t)((t + 1) & 1) * BH;
            atom_st8(hn + (size_t)batch * D_H + colo, u);

            // speculative loads for h_{t+1} (validated next iteration)
            const f16* hs2 = hbuf + (size_t)((t + 1) & 1) * BH + (size_t)b0 * D_H;
            #pragma unroll
            for (int i = 0; i < 32; ++i)
                buf[i] = atom_ld8(hs2 + (size_t)i * D_H + tid * 4);
        } else {
            float4 o; o.x = th0; o.y = th1; o.z = th2; o.w = th3;
            *(float4*)(out + (size_t)batch * D_H + colo) = o;
        }

        // ds_reads of this step must finish before next step's ds_writes
        BARRIER_LGKM();
    }
}

// ===========================================================================
extern "C" void kernel_launch(void* const* d_in, const int* in_sizes, int n_in,
                              void* d_out, int out_size, void* d_ws, size_t ws_size,
                              hipStream_t stream) {
    const float* X     = (const float*)d_in[0];   // [512][128][512]
    const float* h0    = (const float*)d_in[1];   // [128][1024]
    const float* Wenc  = (const float*)d_in[2];   // [512][1024]
    const float* b_enc = (const float*)d_in[3];   // [1024]
    const float* Wh    = (const float*)d_in[4];   // [1024][1024]
    const float* b_h   = (const float*)d_in[5];   // [1024]
    float* out = (float*)d_out;

    char* ws = (char*)d_ws;
    f16* Wx16    = (f16*)(ws + WX_OFF);
    f16* WencT16 = (f16*)(ws + WENC_OFF);
    f16* WhT16   = (f16*)(ws + WH_OFF);
    f16* hbuf    = (f16*)(ws + HBUF_OFF);

    int total = D_IN * D_H + D_H * D_H + BATCH * D_H;
    convert_kernel<<<(total + 255) / 256, 256, 0, stream>>>(Wenc, Wh, h0,
                                                            WencT16, WhT16, hbuf);

    wx_gemm<<<dim3(65536 / 128, D_H / 128), 256, 0, stream>>>(X, WencT16, b_enc, Wx16);

    const int lds_bytes = 2 * 32 * LDSTR * 2;   // 132096
    hipFuncSetAttribute((const void*)rnn_steps,
                        hipFuncAttributeMaxDynamicSharedMemorySize, lds_bytes);
    rnn_steps<<<128, 256, lds_bytes, stream>>>(WhT16, Wx16, b_h, hbuf, out);
}

// Round 6
// 2493.220 us; speedup vs baseline: 1.2924x; 1.2924x over previous
//
#include <hip/hip_runtime.h>
#include <hip/hip_bf16.h>

// ---------------------------------------------------------------------------
// RNN: h_{t+1} = tanh(Wx[t] + h_t @ W_h + b_h),  Wx = X @ W_enc + b_enc
// T=512 B=128 D_IN=512 D_H=1024. fp16 MFMA (16x16x32), fp32 accumulate.
//
// R6 = R4 topology (128 WGs = 4 groups x 32; WG owns 32 h-cols, W_h slice in
// LDS) with a CHEAP READINESS CHANNEL instead of 64KB spin probes:
//   * producer: h stores (tagged, uncached 8B) -> s_waitcnt vmcnt(0)+s_barrier
//     -> tid0 stores flag=t+1 (4B, uncached). Publish is PROMPT (R3's flag
//     failure was deferred publish, not flags per se).
//   * consumer: each wave polls the group's 32 packed flag slots with ONE
//     coalesced 128B uncached load (lane w reads slot w, own slot = ready).
//     Then ONE 64KB slab burst, guaranteed fresh; tags kept as backstop.
//   One barrier per step (vmcnt-drain barrier also guards h_lds reuse).
// ---------------------------------------------------------------------------

typedef _Float16 f16;
typedef f16 f16x8 __attribute__((ext_vector_type(8)));
typedef f16 f16x4 __attribute__((ext_vector_type(4)));
typedef float f32x4 __attribute__((ext_vector_type(4)));
typedef unsigned long long u64;

#define T_STEPS 512
#define BATCH   128
#define D_IN    512
#define D_H     1024
#define BH      (BATCH * D_H)

// ---- workspace layout (bytes) ----
#define WX_OFF    0                         // fp16 Wx [512][128][1024] = 134217728
#define WENC_OFF  (134217728)               // fp16 W_encT [1024][512]  = 1048576
#define WH_OFF    (WENC_OFF + 1048576)      // fp16 W_hT   [1024][1024] = 2097152
#define HBUF_OFF  (WH_OFF + 2097152)        // fp16 hbuf [2][128][1024] = 524288
#define FLG_OFF   (HBUF_OFF + 524288)       // flags: 4 groups * 256B

#define LDSTR   1032    // fp16 row stride (pad +8: 16B-aligned rows, 2-way banks)

// tag bits: LSB of each fp16 lane of the 8B granule (backstop validation)
#define TAGM 0x0001000100010001ULL
__device__ __forceinline__ u64 tag_pat(int s) {
    return ((u64)(s & 1)        * 0x0000000100000001ULL)
         | ((u64)((s >> 1) & 1) * 0x0001000000010000ULL);
}

// ---- relaxed agent-scope atomics: cache-bypassing, no fences ----
__device__ __forceinline__ u64 atom_ld8(const void* p) {
    return __hip_atomic_load((const u64*)p, __ATOMIC_RELAXED, __HIP_MEMORY_SCOPE_AGENT);
}
__device__ __forceinline__ void atom_st8(void* p, u64 v) {
    __hip_atomic_store((u64*)p, v, __ATOMIC_RELAXED, __HIP_MEMORY_SCOPE_AGENT);
}
__device__ __forceinline__ unsigned atom_ld4(const unsigned* p) {
    return __hip_atomic_load(p, __ATOMIC_RELAXED, __HIP_MEMORY_SCOPE_AGENT);
}
__device__ __forceinline__ void atom_st4(unsigned* p, unsigned v) {
    __hip_atomic_store(p, v, __ATOMIC_RELAXED, __HIP_MEMORY_SCOPE_AGENT);
}

#define BARRIER_LGKM() asm volatile("s_waitcnt lgkmcnt(0)\n\ts_barrier" ::: "memory")
// full store-drain barrier: all waves' vmem stores complete, then rendezvous
#define BARRIER_VM0()  asm volatile("s_waitcnt vmcnt(0) lgkmcnt(0)\n\ts_barrier" ::: "memory")

__device__ __forceinline__ float fast_tanh(float v) {
    float ax = __builtin_fabsf(v);
    float tq = __builtin_amdgcn_exp2f(-2.8853900817779268f * ax);   // e^(-2|x|)
    float th = (1.0f - tq) * __builtin_amdgcn_rcpf(1.0f + tq);
    return __builtin_copysignf(th, v);
}

// ===========================================================================
// Phase 0: convert W_enc -> W_encT fp16, W_h -> W_hT fp16, h0 -> hbuf[0] fp16
// ===========================================================================
__global__ void convert_kernel(const float* __restrict__ Wenc,
                               const float* __restrict__ Wh,
                               const float* __restrict__ h0,
                               f16* __restrict__ WencT,
                               f16* __restrict__ WhT,
                               f16* __restrict__ hbuf0) {
    int idx = blockIdx.x * 256 + threadIdx.x;
    if (idx < D_IN * D_H) {                       // W_enc [512][1024]
        int k = idx >> 10, n = idx & 1023;
        WencT[n * D_IN + k] = (f16)Wenc[idx];
    } else if (idx < D_IN * D_H + D_H * D_H) {    // W_h [1024][1024]
        int j = idx - D_IN * D_H;
        int k = j >> 10, n = j & 1023;
        WhT[n * D_H + k] = (f16)Wh[j];
    } else if (idx < D_IN * D_H + D_H * D_H + BATCH * D_H) {
        int j = idx - (D_IN * D_H + D_H * D_H);
        f16 v = (f16)h0[j];
        unsigned short u = __builtin_bit_cast(unsigned short, v) & 0xFFFEu; // tag 0
        hbuf0[j] = __builtin_bit_cast(f16, u);
    }
}

// ===========================================================================
// Phase 1: Wx = X @ W_enc + b_enc   (M=65536, K=512, N=1024), out fp16
// ===========================================================================
__global__ __launch_bounds__(256, 2) void wx_gemm(
        const float* __restrict__ X,
        const f16*   __restrict__ WencT,
        const float* __restrict__ b_enc,
        f16*         __restrict__ Wx) {
    __shared__ f16 A_lds[128 * 72];
    __shared__ f16 B_lds[128 * 72];

    const int m0 = blockIdx.x * 128;
    const int n0 = blockIdx.y * 128;
    const int tid = threadIdx.x;
    const int wave = tid >> 6, lane = tid & 63;
    const int q = lane >> 4, r = lane & 15;
    const int wm = wave >> 1, wn = wave & 1;

    f32x4 acc[4][4] = {};

    for (int kb = 0; kb < D_IN; kb += 64) {
        #pragma unroll
        for (int i = 0; i < 8; ++i) {
            int vec = tid + i * 256;
            int m = vec >> 4, k4 = vec & 15;
            float4 f = *(const float4*)(X + (size_t)(m0 + m) * D_IN + kb + k4 * 4);
            f16x4 h4;
            h4[0] = (f16)f.x; h4[1] = (f16)f.y; h4[2] = (f16)f.z; h4[3] = (f16)f.w;
            *(f16x4*)(A_lds + m * 72 + k4 * 4) = h4;
        }
        #pragma unroll
        for (int i = 0; i < 4; ++i) {
            int vec = tid + i * 256;
            int n = vec >> 3, k8 = vec & 7;
            f16x8 v = *(const f16x8*)(WencT + (size_t)(n0 + n) * D_IN + kb + k8 * 8);
            *(f16x8*)(B_lds + n * 72 + k8 * 8) = v;
        }
        __syncthreads();
        #pragma unroll
        for (int ks = 0; ks < 2; ++ks) {
            f16x8 a[4], b[4];
            #pragma unroll
            for (int i = 0; i < 4; ++i)
                a[i] = *(const f16x8*)(A_lds + (wm * 64 + i * 16 + r) * 72 + ks * 32 + q * 8);
            #pragma unroll
            for (int j = 0; j < 4; ++j)
                b[j] = *(const f16x8*)(B_lds + (wn * 64 + j * 16 + r) * 72 + ks * 32 + q * 8);
            #pragma unroll
            for (int i = 0; i < 4; ++i)
                #pragma unroll
                for (int j = 0; j < 4; ++j)
                    acc[i][j] = __builtin_amdgcn_mfma_f32_16x16x32_f16(a[i], b[j], acc[i][j], 0, 0, 0);
        }
        __syncthreads();
    }
    #pragma unroll
    for (int j = 0; j < 4; ++j) {
        int col = n0 + wn * 64 + j * 16 + r;
        float be = b_enc[col];
        #pragma unroll
        for (int i = 0; i < 4; ++i) {
            int row = m0 + wm * 64 + i * 16 + q * 4;
            #pragma unroll
            for (int ii = 0; ii < 4; ++ii)
                Wx[(size_t)(row + ii) * D_H + col] = (f16)(acc[i][j][ii] + be);
        }
    }
}

// ===========================================================================
// Phase 2: flag-gated tagged scan. 128 WGs x 256 threads.
// ===========================================================================
extern __shared__ char smem_raw[];

__global__ __launch_bounds__(256) void rnn_steps(
        const f16*  __restrict__ WhT,    // [1024][1024] fp16 n-major
        const f16*  __restrict__ Wx,     // [512][128][1024] fp16
        const float* __restrict__ b_h,   // [1024]
        f16*        __restrict__ hbuf,   // [2][128][1024] fp16 (tagged)
        float*      __restrict__ out,    // [128][1024] fp32
        unsigned*   __restrict__ flags) {// [4][64] dwords; group g uses [g*64 .. +32)
    f16* w_lds = (f16*)smem_raw;                  // [32][LDSTR]
    f16* h_lds = (f16*)smem_raw + 32 * LDSTR;     // [32][LDSTR]

    const int wg   = blockIdx.x;
    const int grp  = wg >> 5;                     // group id (batch block)
    const int slc  = wg & 31;                     // column-slice id
    const int b0   = grp * 32;
    const int c0   = slc * 32;
    const int tid  = threadIdx.x;
    const int lane = tid & 63;
    const int wave = tid >> 6;
    const int q = lane >> 4, r = lane & 15;
    const int ct = wave >> 1, bt = wave & 1;

    unsigned* gflags = flags + grp * 64;          // 32 slots, 4B each, one line
    unsigned* myflag = gflags + slc;

    // pin W_h slice: 32 col-rows x 1024 k
    #pragma unroll
    for (int i = 0; i < 16; ++i) {
        int vec = tid + i * 256;
        int n = vec >> 7, k8 = vec & 127;
        f16x8 v = *(const f16x8*)(WhT + (size_t)(c0 + n) * D_H + k8 * 8);
        *(f16x8*)(w_lds + n * LDSTR + k8 * 8) = v;
    }
    const int colo = c0 + ct * 16 + q * 4;        // lane's 4 consecutive cols
    const float4 bhv = *(const float4*)(b_h + colo);
    const int batch = b0 + bt * 16 + r;           // lane's batch
    __syncthreads();                              // w_lds ready

    u64 buf[32];

    for (int t = 0; t < T_STEPS; ++t) {
        const u64 pat = tag_pat(t);
        const f16* hs = hbuf + (size_t)(t & 1) * BH + (size_t)b0 * D_H;

        // prefetch Wx[t] (cached; overlaps the flag poll)
        f16x4 wxv = *(const f16x4*)(Wx + (size_t)t * BH + (size_t)batch * D_H + colo);

        // ---- readiness poll: one coalesced 128B uncached load per round ----
        if (t > 0) {
            const bool mine = (lane < 32) && (lane != slc);   // own slot ready
            const unsigned* slot = gflags + (lane & 31);
            unsigned v = mine ? atom_ld4(slot) : 0xFFFFFFFFu;
            while (__ballot(v < (unsigned)t)) {
                __builtin_amdgcn_s_sleep(1);
                v = mine ? atom_ld4(slot) : 0xFFFFFFFFu;
            }
        }

        // ---- slab read (guaranteed fresh) + tag backstop ----
        #pragma unroll
        for (int i = 0; i < 32; ++i)
            buf[i] = atom_ld8(hs + (size_t)i * D_H + tid * 4);
        for (;;) {
            u64 d = 0;
            #pragma unroll
            for (int i = 0; i < 32; ++i) d |= (buf[i] ^ pat) & TAGM;
            if (!__any(d != 0)) break;
            #pragma unroll
            for (int i = 0; i < 32; ++i)
                buf[i] = atom_ld8(hs + (size_t)i * D_H + tid * 4);
        }

        // ---- h_t -> LDS ----
        #pragma unroll
        for (int i = 0; i < 32; ++i)
            *(u64*)(h_lds + i * LDSTR + tid * 4) = buf[i];
        BARRIER_LGKM();

        // ---- MFMA: D[col][batch] = Wslice(32x1024) * h^T ----
        f32x4 acc0 = {0.f, 0.f, 0.f, 0.f}, acc1 = {0.f, 0.f, 0.f, 0.f};
        #pragma unroll
        for (int kk = 0; kk < 32; kk += 2) {
            f16x8 aw0 = *(const f16x8*)(w_lds + (ct * 16 + r) * LDSTR + kk * 32 + q * 8);
            f16x8 ah0 = *(const f16x8*)(h_lds + (bt * 16 + r) * LDSTR + kk * 32 + q * 8);
            acc0 = __builtin_amdgcn_mfma_f32_16x16x32_f16(aw0, ah0, acc0, 0, 0, 0);
            f16x8 aw1 = *(const f16x8*)(w_lds + (ct * 16 + r) * LDSTR + (kk + 1) * 32 + q * 8);
            f16x8 ah1 = *(const f16x8*)(h_lds + (bt * 16 + r) * LDSTR + (kk + 1) * 32 + q * 8);
            acc1 = __builtin_amdgcn_mfma_f32_16x16x32_f16(aw1, ah1, acc1, 0, 0, 0);
        }

        // ---- epilogue: tanh -> tagged 8B store of h_{t+1} ----
        float th0 = fast_tanh(acc0[0] + acc1[0] + (float)wxv[0] + bhv.x);
        float th1 = fast_tanh(acc0[1] + acc1[1] + (float)wxv[1] + bhv.y);
        float th2 = fast_tanh(acc0[2] + acc1[2] + (float)wxv[2] + bhv.z);
        float th3 = fast_tanh(acc0[3] + acc1[3] + (float)wxv[3] + bhv.w);

        if (t < T_STEPS - 1) {
            f16x4 hv;
            hv[0] = (f16)th0; hv[1] = (f16)th1; hv[2] = (f16)th2; hv[3] = (f16)th3;
            u64 u = (__builtin_bit_cast(u64, hv) & ~TAGM) | tag_pat(t + 1);
            f16* hn = hbuf + (size_t)((t + 1) & 1) * BH;
            atom_st8(hn + (size_t)batch * D_H + colo, u);

            // all 256 threads' h-stores complete at the coherent point, then
            // publish. This barrier also guards h_lds reuse for t+1.
            BARRIER_VM0();
            if (tid == 0) atom_st4(myflag, (unsigned)(t + 1));
        } else {
            float4 o; o.x = th0; o.y = th1; o.z = th2; o.w = th3;
            *(float4*)(out + (size_t)batch * D_H + colo) = o;
        }
    }
}

// ===========================================================================
extern "C" void kernel_launch(void* const* d_in, const int* in_sizes, int n_in,
                              void* d_out, int out_size, void* d_ws, size_t ws_size,
                              hipStream_t stream) {
    const float* X     = (const float*)d_in[0];   // [512][128][512]
    const float* h0    = (const float*)d_in[1];   // [128][1024]
    const float* Wenc  = (const float*)d_in[2];   // [512][1024]
    const float* b_enc = (const float*)d_in[3];   // [1024]
    const float* Wh    = (const float*)d_in[4];   // [1024][1024]
    const float* b_h   = (const float*)d_in[5];   // [1024]
    float* out = (float*)d_out;

    char* ws = (char*)d_ws;
    f16* Wx16    = (f16*)(ws + WX_OFF);
    f16* WencT16 = (f16*)(ws + WENC_OFF);
    f16* WhT16   = (f16*)(ws + WH_OFF);
    f16* hbuf    = (f16*)(ws + HBUF_OFF);
    unsigned* flags = (unsigned*)(ws + FLG_OFF);

    hipMemsetAsync(flags, 0, 4 * 64 * 4, stream);

    int total = D_IN * D_H + D_H * D_H + BATCH * D_H;
    convert_kernel<<<(total + 255) / 256, 256, 0, stream>>>(Wenc, Wh, h0,
                                                            WencT16, WhT16, hbuf);

    wx_gemm<<<dim3(65536 / 128, D_H / 128), 256, 0, stream>>>(X, WencT16, b_enc, Wx16);

    const int lds_bytes = 2 * 32 * LDSTR * 2;   // 132096
    hipFuncSetAttribute((const void*)rnn_steps,
                        hipFuncAttributeMaxDynamicSharedMemorySize, lds_bytes);
    rnn_steps<<<128, 256, lds_bytes, stream>>>(WhT16, Wx16, b_h, hbuf, out, flags);
}